// Round 13
// baseline (180.788 us; speedup 1.0000x reference)
//
#include <hip/hip_runtime.h>
#include <math.h>

#define N_WIRES 8
#define N_LAYERS 6
#define NG 49          // grid per axis (frequencies |n|<=24 -> 49 samples exact)
#define NG2 (NG * NG)  // 2401
#define FPAD 52        // padded row length for F rows (26 x half2)

// ws layout (bytes):
//   E : [0, 76832)       8 x 2401 floats (grid EVs, [i][a*49+b])
//   F : [76832, +40768)  8 x 49 x FPAD _Float16 (2D Fourier coeffs * pi)
#define WS_E_OFF 0
#define WS_F_OFF 76832

typedef _Float16 half2v __attribute__((ext_vector_type(2)));

// ---------------------------------------------------------------------------
// Grid circuit eval, block-per-point (r12-proven). Block g simulates grid
// point g=a*49+b; one amplitude per thread; exchanges via LDS; per-layer
// CNOT chain folded into one Gray-code permutation src = idx ^ (idx>>1).
// ---------------------------------------------------------------------------
__global__ __launch_bounds__(256) void qnn_grid_lds(const float* __restrict__ w,
                                                    float* __restrict__ E) {
    __shared__ float gates[N_LAYERS * N_WIRES * 8];
    __shared__ float2 amps[256];
    __shared__ float partial[4][8];

    const int tid = threadIdx.x;
    const int g = blockIdx.x;
    const int ga = (g * 1338) >> 16;  // g/49, exact for g < 2404
    const int gb = g - ga * NG;
    const float step = (float)(2.0 * M_PI / 49.0);

    if (tid < N_LAYERS * N_WIRES) {
        const int i = tid & 7;
        float wx = w[tid * 3 + 0], wy = w[tid * 3 + 1], wz = w[tid * 3 + 2];
        float sx, cx, sy, cy, sz, cz;
        sincosf(0.5f * wx, &sx, &cx);
        sincosf(0.5f * wy, &sy, &cy);
        sincosf(0.5f * wz, &sz, &cz);
        float A00r = cy * cx, A00i = sy * sx;
        float A01r = -sy * cx, A01i = -cy * sx;
        float A10r = sy * cx, A10i = -cy * sx;
        float A11r = cy * cx, A11i = -sy * sx;
        float U00r = A00r * cz + A00i * sz, U00i = A00i * cz - A00r * sz;
        float U01r = A01r * cz + A01i * sz, U01i = A01i * cz - A01r * sz;
        float U10r = A10r * cz - A10i * sz, U10i = A10i * cz + A10r * sz;
        float U11r = A11r * cz - A11i * sz, U11i = A11i * cz + A11r * sz;
        float V00r, V00i, V01r, V01i, V10r, V10i, V11r, V11i;
        if ((i & 1) == 0) {
            V00r = U01i; V00i = -U01r;
            V01r = U00i; V01i = -U00r;
            V10r = U11i; V10i = -U11r;
            V11r = U10i; V11i = -U10r;
        } else {
            V00r = U01r;  V00i = U01i;
            V01r = -U00r; V01i = -U00i;
            V10r = U11r;  V10i = U11i;
            V11r = -U10r; V11i = -U10i;
        }
        const float xx = (i & 1) ? (step * (float)gb) : (step * (float)ga);
        float se, ce;
        sincosf(0.5f * xx, &se, &ce);
        float* o = gates + tid * 8;
        o[0] = ce * U00r + se * V00r;  o[1] = ce * U00i + se * V00i;
        o[2] = ce * U01r + se * V01r;  o[3] = ce * U01i + se * V01i;
        o[4] = ce * U10r + se * V10r;  o[5] = ce * U10i + se * V10i;
        o[6] = ce * U11r + se * V11r;  o[7] = ce * U11i + se * V11i;
    }

    float ar = (tid == 0) ? 1.0f : 0.0f;
    float ai = 0.0f;
    __syncthreads();

    for (int l = 0; l < N_LAYERS; ++l) {
        #pragma unroll
        for (int i = 0; i < 8; ++i) {
            const float* gm = gates + (l * 8 + i) * 8;
            const int p = 7 - i;
            const int m = 1 << p;
            const int bit = (tid >> p) & 1;
            amps[tid] = make_float2(ar, ai);
            __syncthreads();
            float2 other = amps[tid ^ m];
            float a0r = bit ? other.x : ar, a0i = bit ? other.y : ai;
            float a1r = bit ? ar : other.x, a1i = bit ? ai : other.y;
            float c0r = gm[bit * 4 + 0], c0i = gm[bit * 4 + 1];
            float c1r = gm[bit * 4 + 2], c1i = gm[bit * 4 + 3];
            float nr = c0r * a0r - c0i * a0i + c1r * a1r - c1i * a1i;
            float ni = c0r * a0i + c0i * a0r + c1r * a1i + c1i * a1r;
            __syncthreads();
            ar = nr; ai = ni;
        }
        amps[tid] = make_float2(ar, ai);
        __syncthreads();
        float2 src = amps[tid ^ (tid >> 1)];
        ar = src.x; ai = src.y;
        __syncthreads();
    }

    float p = ar * ar + ai * ai;
    float ev[8];
    #pragma unroll
    for (int i = 0; i < 8; ++i) ev[i] = ((tid >> (7 - i)) & 1) ? -p : p;
    #pragma unroll
    for (int i = 0; i < 8; ++i) {
        #pragma unroll
        for (int s = 1; s < 64; s <<= 1) ev[i] += __shfl_xor(ev[i], s);
    }
    const int wave = tid >> 6, lane = tid & 63;
    if (lane == 0) {
        #pragma unroll
        for (int i = 0; i < 8; ++i) partial[wave][i] = ev[i];
    }
    __syncthreads();
    if (tid < 8) {
        E[tid * NG2 + g] = partial[0][tid] + partial[1][tid] + partial[2][tid] + partial[3][tid];
    }
}

// ---------------------------------------------------------------------------
// Fused separable 2D DFT (r11/r12-proven). Block (kp, i), 64 threads.
// ---------------------------------------------------------------------------
__global__ __launch_bounds__(64) void dft2(const float* __restrict__ E,
                                           _Float16* __restrict__ F) {
    const int kp = blockIdx.x, i = blockIdx.y, t = threadIdx.x;
    __shared__ float Es[NG2];
    __shared__ float H[NG];
    const float step = (float)(2.0 * M_PI / 49.0);

    for (int e = t; e < NG2; e += 64) Es[e] = E[i * NG2 + e];
    __syncthreads();

    if (t < NG) {
        const int b = t;
        float acc = 0.f;
        if (kp == 0) {
            for (int a = 0; a < NG; ++a) acc += Es[a * NG + b];
            acc *= (1.0f / 49.0f);
        } else {
            const int n = (kp + 1) >> 1;
            float cs, ss;
            sincosf(step * (float)n, &ss, &cs);
            float ca = 1.f, sa = 0.f;
            const bool use_cos = (kp & 1);
            for (int a = 0; a < NG; ++a) {
                acc = fmaf(Es[a * NG + b], use_cos ? ca : sa, acc);
                float cn = ca * cs - sa * ss;
                float sn = sa * cs + ca * ss;
                ca = cn; sa = sn;
            }
            acc *= (2.0f / 49.0f);
        }
        H[b] = acc;
    }
    __syncthreads();

    if (t < FPAD) {
        const int l = t;
        const float PI = 3.14159265358979323846f;
        float acc = 0.f;
        if (l < NG) {
            if (l == 0) {
                for (int b = 0; b < NG; ++b) acc += H[b];
                acc *= (PI / 49.0f);
            } else {
                const int n = (l + 1) >> 1;
                float cs, ss;
                sincosf(step * (float)n, &ss, &cs);
                float cb = 1.f, sb = 0.f;
                const bool use_cos = (l & 1);
                for (int b = 0; b < NG; ++b) {
                    acc = fmaf(H[b], use_cos ? cb : sb, acc);
                    float cn = cb * cs - sb * ss;
                    float sn = sb * cs + cb * ss;
                    cb = cn; sb = sn;
                }
                acc *= (2.0f * PI / 49.0f);
            }
        }
        F[(i * NG + kp) * FPAD + l] = (_Float16)acc;
    }
}

// ---------------------------------------------------------------------------
// Final contraction with F staged in LDS. r11/r12 compute structure (2
// outputs/thread, f16 v_dot2, fp32 acc, unroll 4); the only change is the
// load path: the block's two F_i matrices (10.2 KB) are loaded to LDS once,
// coalesced, then all row reads are LDS broadcasts (wave-uniform address),
// bypassing the K$/L2 path that stalled 33% of issue slots.
// ---------------------------------------------------------------------------
#if __has_builtin(__builtin_amdgcn_fdot2)
#define DOT2(a, b, c) __builtin_amdgcn_fdot2((a), (b), (c), false)
#else
#define DOT2(a, b, c) ((float)(a).x * (float)(b).x + (float)(a).y * (float)(b).y + (c))
#endif

#define NROWH2 (FPAD / 2)            // 26 half2 per row
#define FIH2 (NG * NROWH2)           // 1274 half2 per F_i

__device__ __forceinline__ float dot26_lds(const half2v* r, const half2v (&v)[26]) {
    float t0 = 0.f, t1 = 0.f;
    #pragma unroll
    for (int l = 0; l < 26; l += 2) {
        t0 = DOT2(r[l], v[l], t0);
        t1 = DOT2(r[l + 1], v[l + 1], t1);
    }
    return t0 + t1;
}

__global__ __launch_bounds__(256) void contract_kernel(const float* __restrict__ x,
                                                       const _Float16* __restrict__ F,
                                                       float* __restrict__ out, int B) {
    __shared__ half2v Fs[2 * FIH2];  // 2 x 49 x 26 half2 = 10192 B

    // stage this block's two F_i matrices (blockIdx.y selects the pair)
    {
        const half2v* src = (const half2v*)(F + (size_t)(blockIdx.y * 2) * NG * FPAD);
        for (int e = threadIdx.x; e < 2 * FIH2; e += 256) Fs[e] = src[e];
    }

    const int b = blockIdx.x * 256 + threadIdx.x;
    float2 xv;
    float s0 = 0.f, c0 = 1.f, s1 = 0.f, c1 = 1.f;
    if (b < B) {
        xv = ((const float2*)x)[b];
        sincosf(xv.x, &s0, &c0);
        sincosf(xv.y, &s1, &c1);
    }
    __syncthreads();
    if (b >= B) return;

    float v1[FPAD];
    v1[0] = 1.0f; v1[1] = c1; v1[2] = s1;
    #pragma unroll
    for (int n = 2; n <= 24; ++n) {
        v1[2 * n - 1] = v1[2 * n - 3] * c1 - v1[2 * n - 2] * s1;
        v1[2 * n]     = v1[2 * n - 2] * c1 + v1[2 * n - 3] * s1;
    }
    v1[49] = 0.f; v1[50] = 0.f; v1[51] = 0.f;

    half2v v1h[26];
    #pragma unroll
    for (int l = 0; l < 26; ++l) {
        half2v h;
        h.x = (_Float16)v1[2 * l];
        h.y = (_Float16)v1[2 * l + 1];
        v1h[l] = h;
    }

    const half2v* base0 = Fs;
    const half2v* base1 = Fs + FIH2;

    float acc0 = dot26_lds(base0, v1h);  // n=0 row
    float acc1 = dot26_lds(base1, v1h);
    float Ck = c0, Sk = s0;
    const half2v* rp0 = base0 + NROWH2;
    const half2v* rp1 = base1 + NROWH2;

    #pragma unroll 4
    for (int n = 1; n <= 24; ++n) {
        float tC0 = dot26_lds(rp0, v1h);
        float tS0 = dot26_lds(rp0 + NROWH2, v1h);
        float tC1 = dot26_lds(rp1, v1h);
        float tS1 = dot26_lds(rp1 + NROWH2, v1h);
        acc0 = fmaf(Ck, tC0, acc0);
        acc0 = fmaf(Sk, tS0, acc0);
        acc1 = fmaf(Ck, tC1, acc1);
        acc1 = fmaf(Sk, tS1, acc1);
        float Cn = Ck * c0 - Sk * s0;
        float Sn = Sk * c0 + Ck * s0;
        Ck = Cn; Sk = Sn;
        rp0 += 2 * NROWH2;
        rp1 += 2 * NROWH2;
    }

    float* o = out + (size_t)b * 8 + blockIdx.y * 2;
    o[0] = acc0;
    o[1] = acc1;
}

extern "C" void kernel_launch(void* const* d_in, const int* in_sizes, int n_in,
                              void* d_out, int out_size, void* d_ws, size_t ws_size,
                              hipStream_t stream) {
    (void)n_in; (void)out_size; (void)ws_size;
    const float* x = (const float*)d_in[0];
    const float* w = (const float*)d_in[1];
    float* out = (float*)d_out;
    char* ws = (char*)d_ws;
    float* E = (float*)(ws + WS_E_OFF);
    _Float16* F = (_Float16*)(ws + WS_F_OFF);
    const int B = in_sizes[0] / 2;

    hipLaunchKernelGGL(qnn_grid_lds, dim3(NG2), dim3(256), 0, stream, w, E);
    hipLaunchKernelGGL(dft2, dim3(NG, 8), dim3(64), 0, stream, E, F);
    hipLaunchKernelGGL(contract_kernel, dim3((B + 255) / 256, 4), dim3(256), 0, stream,
                       x, F, out, B);
}

// Round 14
// 139.236 us; speedup vs baseline: 1.2984x; 1.2984x over previous
//
#include <hip/hip_runtime.h>
#include <math.h>

#define N_WIRES 8
#define N_LAYERS 6
#define NG 49          // grid per axis (frequencies |n|<=24 -> 49 samples exact)
#define NG2 (NG * NG)  // 2401
#define FPAD 52        // padded row length for F rows (26 x half2)

// ws layout (bytes):
//   E : [0, 76832)       8 x 2401 floats (grid EVs, [i][a*49+b])
//   F : [76832, +40768)  8 x 49 x FPAD _Float16 (2D Fourier coeffs * pi)
#define WS_E_OFF 0
#define WS_F_OFF 76832

typedef _Float16 half2v __attribute__((ext_vector_type(2)));

// ---------------------------------------------------------------------------
// Grid circuit eval, block-per-point (r12-proven, byte-identical). Block g
// simulates grid point g=a*49+b; one amplitude per thread; exchanges via LDS;
// per-layer CNOT chain folded into one Gray permutation src = idx ^ (idx>>1).
// ---------------------------------------------------------------------------
__global__ __launch_bounds__(256) void qnn_grid_lds(const float* __restrict__ w,
                                                    float* __restrict__ E) {
    __shared__ float gates[N_LAYERS * N_WIRES * 8];
    __shared__ float2 amps[256];
    __shared__ float partial[4][8];

    const int tid = threadIdx.x;
    const int g = blockIdx.x;
    const int ga = (g * 1338) >> 16;  // g/49, exact for g < 2404
    const int gb = g - ga * NG;
    const float step = (float)(2.0 * M_PI / 49.0);

    if (tid < N_LAYERS * N_WIRES) {
        const int i = tid & 7;
        float wx = w[tid * 3 + 0], wy = w[tid * 3 + 1], wz = w[tid * 3 + 2];
        float sx, cx, sy, cy, sz, cz;
        sincosf(0.5f * wx, &sx, &cx);
        sincosf(0.5f * wy, &sy, &cy);
        sincosf(0.5f * wz, &sz, &cz);
        float A00r = cy * cx, A00i = sy * sx;
        float A01r = -sy * cx, A01i = -cy * sx;
        float A10r = sy * cx, A10i = -cy * sx;
        float A11r = cy * cx, A11i = -sy * sx;
        float U00r = A00r * cz + A00i * sz, U00i = A00i * cz - A00r * sz;
        float U01r = A01r * cz + A01i * sz, U01i = A01i * cz - A01r * sz;
        float U10r = A10r * cz - A10i * sz, U10i = A10i * cz + A10r * sz;
        float U11r = A11r * cz - A11i * sz, U11i = A11i * cz + A11r * sz;
        float V00r, V00i, V01r, V01i, V10r, V10i, V11r, V11i;
        if ((i & 1) == 0) {
            V00r = U01i; V00i = -U01r;
            V01r = U00i; V01i = -U00r;
            V10r = U11i; V10i = -U11r;
            V11r = U10i; V11i = -U10r;
        } else {
            V00r = U01r;  V00i = U01i;
            V01r = -U00r; V01i = -U00i;
            V10r = U11r;  V10i = U11i;
            V11r = -U10r; V11i = -U10i;
        }
        const float xx = (i & 1) ? (step * (float)gb) : (step * (float)ga);
        float se, ce;
        sincosf(0.5f * xx, &se, &ce);
        float* o = gates + tid * 8;
        o[0] = ce * U00r + se * V00r;  o[1] = ce * U00i + se * V00i;
        o[2] = ce * U01r + se * V01r;  o[3] = ce * U01i + se * V01i;
        o[4] = ce * U10r + se * V10r;  o[5] = ce * U10i + se * V10i;
        o[6] = ce * U11r + se * V11r;  o[7] = ce * U11i + se * V11i;
    }

    float ar = (tid == 0) ? 1.0f : 0.0f;
    float ai = 0.0f;
    __syncthreads();

    for (int l = 0; l < N_LAYERS; ++l) {
        #pragma unroll
        for (int i = 0; i < 8; ++i) {
            const float* gm = gates + (l * 8 + i) * 8;
            const int p = 7 - i;
            const int m = 1 << p;
            const int bit = (tid >> p) & 1;
            amps[tid] = make_float2(ar, ai);
            __syncthreads();
            float2 other = amps[tid ^ m];
            float a0r = bit ? other.x : ar, a0i = bit ? other.y : ai;
            float a1r = bit ? ar : other.x, a1i = bit ? ai : other.y;
            float c0r = gm[bit * 4 + 0], c0i = gm[bit * 4 + 1];
            float c1r = gm[bit * 4 + 2], c1i = gm[bit * 4 + 3];
            float nr = c0r * a0r - c0i * a0i + c1r * a1r - c1i * a1i;
            float ni = c0r * a0i + c0i * a0r + c1r * a1i + c1i * a1r;
            __syncthreads();
            ar = nr; ai = ni;
        }
        amps[tid] = make_float2(ar, ai);
        __syncthreads();
        float2 src = amps[tid ^ (tid >> 1)];
        ar = src.x; ai = src.y;
        __syncthreads();
    }

    float p = ar * ar + ai * ai;
    float ev[8];
    #pragma unroll
    for (int i = 0; i < 8; ++i) ev[i] = ((tid >> (7 - i)) & 1) ? -p : p;
    #pragma unroll
    for (int i = 0; i < 8; ++i) {
        #pragma unroll
        for (int s = 1; s < 64; s <<= 1) ev[i] += __shfl_xor(ev[i], s);
    }
    const int wave = tid >> 6, lane = tid & 63;
    if (lane == 0) {
        #pragma unroll
        for (int i = 0; i < 8; ++i) partial[wave][i] = ev[i];
    }
    __syncthreads();
    if (tid < 8) {
        E[tid * NG2 + g] = partial[0][tid] + partial[1][tid] + partial[2][tid] + partial[3][tid];
    }
}

// ---------------------------------------------------------------------------
// Fused separable 2D DFT (r11/r12-proven, byte-identical). Block (kp, i).
// ---------------------------------------------------------------------------
__global__ __launch_bounds__(64) void dft2(const float* __restrict__ E,
                                           _Float16* __restrict__ F) {
    const int kp = blockIdx.x, i = blockIdx.y, t = threadIdx.x;
    __shared__ float Es[NG2];
    __shared__ float H[NG];
    const float step = (float)(2.0 * M_PI / 49.0);

    for (int e = t; e < NG2; e += 64) Es[e] = E[i * NG2 + e];
    __syncthreads();

    if (t < NG) {
        const int b = t;
        float acc = 0.f;
        if (kp == 0) {
            for (int a = 0; a < NG; ++a) acc += Es[a * NG + b];
            acc *= (1.0f / 49.0f);
        } else {
            const int n = (kp + 1) >> 1;
            float cs, ss;
            sincosf(step * (float)n, &ss, &cs);
            float ca = 1.f, sa = 0.f;
            const bool use_cos = (kp & 1);
            for (int a = 0; a < NG; ++a) {
                acc = fmaf(Es[a * NG + b], use_cos ? ca : sa, acc);
                float cn = ca * cs - sa * ss;
                float sn = sa * cs + ca * ss;
                ca = cn; sa = sn;
            }
            acc *= (2.0f / 49.0f);
        }
        H[b] = acc;
    }
    __syncthreads();

    if (t < FPAD) {
        const int l = t;
        const float PI = 3.14159265358979323846f;
        float acc = 0.f;
        if (l < NG) {
            if (l == 0) {
                for (int b = 0; b < NG; ++b) acc += H[b];
                acc *= (PI / 49.0f);
            } else {
                const int n = (l + 1) >> 1;
                float cs, ss;
                sincosf(step * (float)n, &ss, &cs);
                float cb = 1.f, sb = 0.f;
                const bool use_cos = (l & 1);
                for (int b = 0; b < NG; ++b) {
                    acc = fmaf(H[b], use_cos ? cb : sb, acc);
                    float cn = cb * cs - sb * ss;
                    float sn = sb * cs + cb * ss;
                    cb = cn; sb = sn;
                }
                acc *= (2.0f * PI / 49.0f);
            }
        }
        F[(i * NG + kp) * FPAD + l] = (_Float16)acc;
    }
}

// ---------------------------------------------------------------------------
// Final contraction, 2 BATCHES x 1 OUTPUT per thread. Load path identical to
// r12 (global wave-uniform rows -> scalar s_loads feeding v_dot2 — r13 proved
// the LDS alternative is strictly worse). Each fetched F row now feeds TWO
// dot26 (one per batch): scalar traffic per FLOP halves vs r12's 2-output
// form. grid (B/512, 8) -> 8192 waves = 8/SIMD, each wave streams one F_i
// (10.2 KB). Unroll 2 keeps in-flight scalar volume ~= r12-unroll4 while
// holding VGPR <= 64.
// ---------------------------------------------------------------------------
#if __has_builtin(__builtin_amdgcn_fdot2)
#define DOT2(a, b, c) __builtin_amdgcn_fdot2((a), (b), (c), false)
#else
#define DOT2(a, b, c) ((float)(a).x * (float)(b).x + (float)(a).y * (float)(b).y + (c))
#endif

__device__ __forceinline__ float dot26(const half2v* __restrict__ r, const half2v (&v)[26]) {
    float t0 = 0.f, t1 = 0.f;
    #pragma unroll
    for (int l = 0; l < 26; l += 2) {
        t0 = DOT2(r[l], v[l], t0);
        t1 = DOT2(r[l + 1], v[l + 1], t1);
    }
    return t0 + t1;
}

__device__ __forceinline__ void build_v1h(float c1, float s1, half2v (&v1h)[26]) {
    float v1[FPAD];
    v1[0] = 1.0f; v1[1] = c1; v1[2] = s1;
    #pragma unroll
    for (int n = 2; n <= 24; ++n) {
        v1[2 * n - 1] = v1[2 * n - 3] * c1 - v1[2 * n - 2] * s1;
        v1[2 * n]     = v1[2 * n - 2] * c1 + v1[2 * n - 3] * s1;
    }
    v1[49] = 0.f; v1[50] = 0.f; v1[51] = 0.f;
    #pragma unroll
    for (int l = 0; l < 26; ++l) {
        half2v h;
        h.x = (_Float16)v1[2 * l];
        h.y = (_Float16)v1[2 * l + 1];
        v1h[l] = h;
    }
}

__global__ __launch_bounds__(256) void contract_kernel(const float* __restrict__ x,
                                                       const _Float16* __restrict__ F,
                                                       float* __restrict__ out, int B) {
    const int b0 = blockIdx.x * 512 + threadIdx.x;
    const int b1 = b0 + 256;
    const int i = blockIdx.y;
    if (b0 >= B) return;

    float2 xv0 = ((const float2*)x)[b0];
    float s00, c00, s10, c10;
    sincosf(xv0.x, &s00, &c00);
    sincosf(xv0.y, &s10, &c10);
    half2v v1h0[26];
    build_v1h(c10, s10, v1h0);

    // B = 131072 is divisible by 512, so b1 < B whenever b0 < B; guard anyway
    const bool has1 = (b1 < B);
    float2 xv1 = has1 ? ((const float2*)x)[b1] : xv0;
    float s01, c01, s11, c11;
    sincosf(xv1.x, &s01, &c01);
    sincosf(xv1.y, &s11, &c11);
    half2v v1h1[26];
    build_v1h(c11, s11, v1h1);

    const half2v* base = (const half2v*)(F + (size_t)i * NG * FPAD);

    float acc0 = dot26(base, v1h0);  // n=0 row
    float acc1 = dot26(base, v1h1);
    float Ck0 = c00, Sk0 = s00;
    float Ck1 = c01, Sk1 = s01;
    const half2v* rp = base + (FPAD / 2);

    #pragma unroll 2
    for (int n = 1; n <= 24; ++n) {
        float tC0 = dot26(rp, v1h0);
        float tC1 = dot26(rp, v1h1);
        float tS0 = dot26(rp + (FPAD / 2), v1h0);
        float tS1 = dot26(rp + (FPAD / 2), v1h1);
        acc0 = fmaf(Ck0, tC0, acc0);
        acc0 = fmaf(Sk0, tS0, acc0);
        acc1 = fmaf(Ck1, tC1, acc1);
        acc1 = fmaf(Sk1, tS1, acc1);
        float Cn0 = Ck0 * c00 - Sk0 * s00, Sn0 = Sk0 * c00 + Ck0 * s00;
        Ck0 = Cn0; Sk0 = Sn0;
        float Cn1 = Ck1 * c01 - Sk1 * s01, Sn1 = Sk1 * c01 + Ck1 * s01;
        Ck1 = Cn1; Sk1 = Sn1;
        rp += FPAD;  // 2 rows of 26 half2
    }

    out[(size_t)b0 * 8 + i] = acc0;
    if (has1) out[(size_t)b1 * 8 + i] = acc1;
}

extern "C" void kernel_launch(void* const* d_in, const int* in_sizes, int n_in,
                              void* d_out, int out_size, void* d_ws, size_t ws_size,
                              hipStream_t stream) {
    (void)n_in; (void)out_size; (void)ws_size;
    const float* x = (const float*)d_in[0];
    const float* w = (const float*)d_in[1];
    float* out = (float*)d_out;
    char* ws = (char*)d_ws;
    float* E = (float*)(ws + WS_E_OFF);
    _Float16* F = (_Float16*)(ws + WS_F_OFF);
    const int B = in_sizes[0] / 2;

    hipLaunchKernelGGL(qnn_grid_lds, dim3(NG2), dim3(256), 0, stream, w, E);
    hipLaunchKernelGGL(dft2, dim3(NG, 8), dim3(64), 0, stream, E, F);
    hipLaunchKernelGGL(contract_kernel, dim3((B + 511) / 512, 8), dim3(256), 0, stream,
                       x, F, out, B);
}

// Round 15
// 109.230 us; speedup vs baseline: 1.6551x; 1.2747x over previous
//
#include <hip/hip_runtime.h>
#include <math.h>

#define N_WIRES 8
#define N_LAYERS 6
#define NG 49          // grid per axis (frequencies |n|<=24 -> 49 samples exact)
#define NG2 (NG * NG)  // 2401

// ws layout (bytes):
//   E  : [0, 76832)        8 x 2401 floats (grid EVs, [i][a*49+b])
//   Fb : [76832, +65536)   MFMA-B-fragment-ordered f16 F (pi folded):
//        frag fid=((i*4+ntile)*2+chunk): 64 lanes x 8 f16;
//        lane q*16+n, elem j  =  F_i[k=ntile*16+n][l=chunk*32+q*8+j]
//        (zero for k>=49 or l>=52)
#define WS_E_OFF 0
#define WS_FB_OFF 76832

typedef _Float16 half8 __attribute__((ext_vector_type(8)));
typedef float f32x4 __attribute__((ext_vector_type(4)));

// ---------------------------------------------------------------------------
// Grid circuit eval, block-per-point (r12-proven, byte-identical).
// ---------------------------------------------------------------------------
__global__ __launch_bounds__(256) void qnn_grid_lds(const float* __restrict__ w,
                                                    float* __restrict__ E) {
    __shared__ float gates[N_LAYERS * N_WIRES * 8];
    __shared__ float2 amps[256];
    __shared__ float partial[4][8];

    const int tid = threadIdx.x;
    const int g = blockIdx.x;
    const int ga = (g * 1338) >> 16;  // g/49, exact for g < 2404
    const int gb = g - ga * NG;
    const float step = (float)(2.0 * M_PI / 49.0);

    if (tid < N_LAYERS * N_WIRES) {
        const int i = tid & 7;
        float wx = w[tid * 3 + 0], wy = w[tid * 3 + 1], wz = w[tid * 3 + 2];
        float sx, cx, sy, cy, sz, cz;
        sincosf(0.5f * wx, &sx, &cx);
        sincosf(0.5f * wy, &sy, &cy);
        sincosf(0.5f * wz, &sz, &cz);
        float A00r = cy * cx, A00i = sy * sx;
        float A01r = -sy * cx, A01i = -cy * sx;
        float A10r = sy * cx, A10i = -cy * sx;
        float A11r = cy * cx, A11i = -sy * sx;
        float U00r = A00r * cz + A00i * sz, U00i = A00i * cz - A00r * sz;
        float U01r = A01r * cz + A01i * sz, U01i = A01i * cz - A01r * sz;
        float U10r = A10r * cz - A10i * sz, U10i = A10i * cz + A10r * sz;
        float U11r = A11r * cz - A11i * sz, U11i = A11i * cz + A11r * sz;
        float V00r, V00i, V01r, V01i, V10r, V10i, V11r, V11i;
        if ((i & 1) == 0) {
            V00r = U01i; V00i = -U01r;
            V01r = U00i; V01i = -U00r;
            V10r = U11i; V10i = -U11r;
            V11r = U10i; V11i = -U10r;
        } else {
            V00r = U01r;  V00i = U01i;
            V01r = -U00r; V01i = -U00i;
            V10r = U11r;  V10i = U11i;
            V11r = -U10r; V11i = -U10i;
        }
        const float xx = (i & 1) ? (step * (float)gb) : (step * (float)ga);
        float se, ce;
        sincosf(0.5f * xx, &se, &ce);
        float* o = gates + tid * 8;
        o[0] = ce * U00r + se * V00r;  o[1] = ce * U00i + se * V00i;
        o[2] = ce * U01r + se * V01r;  o[3] = ce * U01i + se * V01i;
        o[4] = ce * U10r + se * V10r;  o[5] = ce * U10i + se * V10i;
        o[6] = ce * U11r + se * V11r;  o[7] = ce * U11i + se * V11i;
    }

    float ar = (tid == 0) ? 1.0f : 0.0f;
    float ai = 0.0f;
    __syncthreads();

    for (int l = 0; l < N_LAYERS; ++l) {
        #pragma unroll
        for (int i = 0; i < 8; ++i) {
            const float* gm = gates + (l * 8 + i) * 8;
            const int p = 7 - i;
            const int m = 1 << p;
            const int bit = (tid >> p) & 1;
            amps[tid] = make_float2(ar, ai);
            __syncthreads();
            float2 other = amps[tid ^ m];
            float a0r = bit ? other.x : ar, a0i = bit ? other.y : ai;
            float a1r = bit ? ar : other.x, a1i = bit ? ai : other.y;
            float c0r = gm[bit * 4 + 0], c0i = gm[bit * 4 + 1];
            float c1r = gm[bit * 4 + 2], c1i = gm[bit * 4 + 3];
            float nr = c0r * a0r - c0i * a0i + c1r * a1r - c1i * a1i;
            float ni = c0r * a0i + c0i * a0r + c1r * a1i + c1i * a1r;
            __syncthreads();
            ar = nr; ai = ni;
        }
        amps[tid] = make_float2(ar, ai);
        __syncthreads();
        float2 src = amps[tid ^ (tid >> 1)];
        ar = src.x; ai = src.y;
        __syncthreads();
    }

    float p = ar * ar + ai * ai;
    float ev[8];
    #pragma unroll
    for (int i = 0; i < 8; ++i) ev[i] = ((tid >> (7 - i)) & 1) ? -p : p;
    #pragma unroll
    for (int i = 0; i < 8; ++i) {
        #pragma unroll
        for (int s = 1; s < 64; s <<= 1) ev[i] += __shfl_xor(ev[i], s);
    }
    const int wave = tid >> 6, lane = tid & 63;
    if (lane == 0) {
        #pragma unroll
        for (int i = 0; i < 8; ++i) partial[wave][i] = ev[i];
    }
    __syncthreads();
    if (tid < 8) {
        E[tid * NG2 + g] = partial[0][tid] + partial[1][tid] + partial[2][tid] + partial[3][tid];
    }
}

// ---------------------------------------------------------------------------
// Fused separable 2D DFT, now writing MFMA-B-fragment-ordered f16 output.
// Grid (64, 8) = (kp, i); kp>=49 rows write zeros (K-pad for MFMA).
// Thread t = l in [0,64); l>=49 compute-zero (l in [49,52) is zero anyway by
// F col count 52... cols l>=52 zero; 49<=l<52 are valid F columns).
// ---------------------------------------------------------------------------
__global__ __launch_bounds__(64) void dft2(const float* __restrict__ E,
                                           _Float16* __restrict__ Fb) {
    const int kp = blockIdx.x, i = blockIdx.y, t = threadIdx.x;
    __shared__ float Es[NG2];
    __shared__ float H[NG];
    const float step = (float)(2.0 * M_PI / 49.0);

    if (kp < NG) {
        for (int e = t; e < NG2; e += 64) Es[e] = E[i * NG2 + e];
    }
    __syncthreads();

    if (kp < NG && t < NG) {
        const int b = t;
        float acc = 0.f;
        if (kp == 0) {
            for (int a = 0; a < NG; ++a) acc += Es[a * NG + b];
            acc *= (1.0f / 49.0f);
        } else {
            const int n = (kp + 1) >> 1;
            float cs, ss;
            sincosf(step * (float)n, &ss, &cs);
            float ca = 1.f, sa = 0.f;
            const bool use_cos = (kp & 1);
            for (int a = 0; a < NG; ++a) {
                acc = fmaf(Es[a * NG + b], use_cos ? ca : sa, acc);
                float cn = ca * cs - sa * ss;
                float sn = sa * cs + ca * ss;
                ca = cn; sa = sn;
            }
            acc *= (2.0f / 49.0f);
        }
        H[b] = acc;
    }
    __syncthreads();

    const int l = t;
    const float PI = 3.14159265358979323846f;
    float acc = 0.f;
    if (kp < NG && l < NG) {
        if (l == 0) {
            for (int b = 0; b < NG; ++b) acc += H[b];
            acc *= (PI / 49.0f);
        } else {
            const int n = (l + 1) >> 1;
            float cs, ss;
            sincosf(step * (float)n, &ss, &cs);
            float cb = 1.f, sb = 0.f;
            const bool use_cos = (l & 1);
            for (int b = 0; b < NG; ++b) {
                acc = fmaf(H[b], use_cos ? cb : sb, acc);
                float cn = cb * cs - sb * ss;
                float sn = sb * cs + cb * ss;
                cb = cn; sb = sn;
            }
            acc *= (2.0f * PI / 49.0f);
        }
    }
    // scatter into B-fragment layout
    {
        const int ntile = kp >> 4, n = kp & 15;
        const int chunk = l >> 5, lrem = l & 31;
        const int q = lrem >> 3, j = lrem & 7;
        const int fid = (i * 4 + ntile) * 2 + chunk;
        Fb[fid * 512 + (q * 16 + n) * 8 + j] = (_Float16)acc;
    }
}

// ---------------------------------------------------------------------------
// MFMA contraction. Block = 64 batches (4 waves x 16), blockIdx.y = i-pair.
// Stage 1 (MFMA f16): T_i[b,k] = sum_l v1[b,l] * F_i[k,l]
//   A[m=lane&15][kk=(lane>>4)*8+j] = v1[batch][l]   (m120-verified layout)
//   B[kk][n=lane&15] = F_i[k=n(+16nt)][l=kk(+32c)]  (loaded pre-packed)
//   C: col=lane&15=k, row=(lane>>4)*4+reg=batch     (m89-verified)
// Stage 2 (VALU): out[b,i] = sum_k v0[b,k]*T -> LDS v0 table (padded row 68
// for 2-way-max banking), per-lane FMA, 16-lane butterfly, scatter store.
// ---------------------------------------------------------------------------
#define V0PAD 68

__global__ __launch_bounds__(256) void contract_mfma(const float* __restrict__ x,
                                                     const _Float16* __restrict__ Fb,
                                                     float* __restrict__ out, int B) {
    __shared__ float xs0[64], xs1[64];
    __shared__ float v0t[64 * V0PAD];  // 17.4 KB

    const int tid = threadIdx.x;
    const int bbase = blockIdx.x * 64;
    const int i0 = blockIdx.y * 2;
    if (bbase >= B) return;

    if (tid < 64) {
        float2 xv = ((const float2*)x)[bbase + tid];
        xs0[tid] = xv.x;
        xs1[tid] = xv.y;
    }
    __syncthreads();

    // ---- v0 table: thread t -> batch b=t&63, k-segment s=t>>6 (16 k's) ----
    {
        const int b = tid & 63, s = tid >> 6;
        const float x0 = xs0[b];
        float c1, s1;
        sincosf(x0, &s1, &c1);
        float cb, sb;
        sincosf((float)(8 * s) * x0, &sb, &cb);
        float* row = v0t + b * V0PAD + 16 * s;
        const int k0 = 16 * s;
        row[0] = (k0 == 0) ? 1.0f : ((k0 < NG) ? sb : 0.0f);
        float cm = cb, sm = sb;
        #pragma unroll
        for (int j = 1; j < 16; ++j) {
            if (j & 1) {
                float c2 = cm * c1 - sm * s1, s2 = sm * c1 + cm * s1;
                cm = c2; sm = s2;
            }
            float val = (j & 1) ? cm : sm;
            row[j] = ((k0 + j) < NG) ? val : 0.0f;
        }
    }

    const int lane = tid & 63;
    const int w = tid >> 6;
    const int q = lane >> 4;

    // ---- A fragments: v1 of this lane's batch at l = q*8+j (+32*chunk) ----
    const float x1v = xs1[w * 16 + (lane & 15)];
    float c1, s1;
    sincosf(x1v, &s1, &c1);
    half8 afrag[2];
    #pragma unroll
    for (int c = 0; c < 2; ++c) {
        const int l0 = c * 32 + q * 8;
        float cb, sb;
        sincosf((float)(l0 >> 1) * x1v, &sb, &cb);
        float vals[8];
        vals[0] = (l0 == 0) ? 1.0f : sb;
        float cm = cb, sm = sb;
        #pragma unroll
        for (int j = 1; j < 8; ++j) {
            if (j & 1) {
                float c2 = cm * c1 - sm * s1, s2 = sm * c1 + cm * s1;
                cm = c2; sm = s2;
            }
            vals[j] = (j & 1) ? cm : sm;
        }
        #pragma unroll
        for (int j = 0; j < 8; ++j) {
            afrag[c][j] = (_Float16)(((l0 + j) < 52) ? vals[j] : 0.0f);
        }
    }

    // ---- B fragments: 2 i x 4 ntiles x 2 chunks, pre-packed in Fb ----
    const half8* FB = (const half8*)Fb;
    half8 bfrag[16];
    #pragma unroll
    for (int ii = 0; ii < 2; ++ii)
        #pragma unroll
        for (int nt = 0; nt < 4; ++nt)
            #pragma unroll
            for (int c = 0; c < 2; ++c) {
                const int fid = ((i0 + ii) * 4 + nt) * 2 + c;
                bfrag[(ii * 4 + nt) * 2 + c] = FB[fid * 64 + lane];
            }

    // ---- MFMAs ----
    f32x4 acc[8];
    #pragma unroll
    for (int t = 0; t < 8; ++t) {
        f32x4 z = {0.f, 0.f, 0.f, 0.f};
        acc[t] = __builtin_amdgcn_mfma_f32_16x16x32_f16(afrag[0], bfrag[t * 2 + 0], z, 0, 0, 0);
        acc[t] = __builtin_amdgcn_mfma_f32_16x16x32_f16(afrag[1], bfrag[t * 2 + 1], acc[t], 0, 0, 0);
    }

    __syncthreads();  // v0t ready

    // ---- epilogue: weight by v0, reduce over k ----
    float res[2][4];
    #pragma unroll
    for (int ii = 0; ii < 2; ++ii)
        #pragma unroll
        for (int r = 0; r < 4; ++r) res[ii][r] = 0.f;

    #pragma unroll
    for (int ii = 0; ii < 2; ++ii)
        #pragma unroll
        for (int nt = 0; nt < 4; ++nt) {
            f32x4 a = acc[ii * 4 + nt];
            #pragma unroll
            for (int r = 0; r < 4; ++r) {
                const int bloc = w * 16 + q * 4 + r;
                float v0 = v0t[bloc * V0PAD + nt * 16 + (lane & 15)];
                res[ii][r] = fmaf(a[r], v0, res[ii][r]);
            }
        }

    #pragma unroll
    for (int ii = 0; ii < 2; ++ii)
        #pragma unroll
        for (int r = 0; r < 4; ++r) {
            float v = res[ii][r];
            v += __shfl_xor(v, 1);
            v += __shfl_xor(v, 2);
            v += __shfl_xor(v, 4);
            v += __shfl_xor(v, 8);
            res[ii][r] = v;
        }

    if ((lane & 15) == 0) {
        #pragma unroll
        for (int r = 0; r < 4; ++r) {
            const int b = bbase + w * 16 + q * 4 + r;
            out[(size_t)b * 8 + i0 + 0] = res[0][r];
            out[(size_t)b * 8 + i0 + 1] = res[1][r];
        }
    }
}

extern "C" void kernel_launch(void* const* d_in, const int* in_sizes, int n_in,
                              void* d_out, int out_size, void* d_ws, size_t ws_size,
                              hipStream_t stream) {
    (void)n_in; (void)out_size; (void)ws_size;
    const float* x = (const float*)d_in[0];
    const float* w = (const float*)d_in[1];
    float* out = (float*)d_out;
    char* ws = (char*)d_ws;
    float* E = (float*)(ws + WS_E_OFF);
    _Float16* Fb = (_Float16*)(ws + WS_FB_OFF);
    const int B = in_sizes[0] / 2;

    hipLaunchKernelGGL(qnn_grid_lds, dim3(NG2), dim3(256), 0, stream, w, E);
    hipLaunchKernelGGL(dft2, dim3(64, 8), dim3(64), 0, stream, E, Fb);
    hipLaunchKernelGGL(contract_mfma, dim3((B + 63) / 64, 4), dim3(256), 0, stream,
                       x, Fb, out, B);
}

// Round 16
// 107.849 us; speedup vs baseline: 1.6763x; 1.0128x over previous
//
#include <hip/hip_runtime.h>
#include <math.h>

#define N_WIRES 8
#define N_LAYERS 6
#define NG 49          // grid per axis (frequencies |n|<=24 -> 49 samples exact)
#define NG2 (NG * NG)  // 2401

// ws layout (bytes):
//   E  : [0, 76832)        8 x 2401 floats (grid EVs, [i][a*49+b])
//   Fb : [76832, +65536)   MFMA-B-fragment-ordered f16 F (pi folded):
//        frag fid=((i*4+ntile)*2+chunk): 64 lanes x 8 f16;
//        lane q*16+n, elem j  =  F_i[k=ntile*16+n][l=chunk*32+q*8+j]
//        (zero for k>=49 or l>=52)
#define WS_E_OFF 0
#define WS_FB_OFF 76832

typedef _Float16 half8 __attribute__((ext_vector_type(8)));
typedef float f32x4 __attribute__((ext_vector_type(4)));

// ---------------------------------------------------------------------------
// Grid circuit eval, block-per-point (r12/r15-proven, byte-identical).
// ---------------------------------------------------------------------------
__global__ __launch_bounds__(256) void qnn_grid_lds(const float* __restrict__ w,
                                                    float* __restrict__ E) {
    __shared__ float gates[N_LAYERS * N_WIRES * 8];
    __shared__ float2 amps[256];
    __shared__ float partial[4][8];

    const int tid = threadIdx.x;
    const int g = blockIdx.x;
    const int ga = (g * 1338) >> 16;  // g/49, exact for g < 2404
    const int gb = g - ga * NG;
    const float step = (float)(2.0 * M_PI / 49.0);

    if (tid < N_LAYERS * N_WIRES) {
        const int i = tid & 7;
        float wx = w[tid * 3 + 0], wy = w[tid * 3 + 1], wz = w[tid * 3 + 2];
        float sx, cx, sy, cy, sz, cz;
        sincosf(0.5f * wx, &sx, &cx);
        sincosf(0.5f * wy, &sy, &cy);
        sincosf(0.5f * wz, &sz, &cz);
        float A00r = cy * cx, A00i = sy * sx;
        float A01r = -sy * cx, A01i = -cy * sx;
        float A10r = sy * cx, A10i = -cy * sx;
        float A11r = cy * cx, A11i = -sy * sx;
        float U00r = A00r * cz + A00i * sz, U00i = A00i * cz - A00r * sz;
        float U01r = A01r * cz + A01i * sz, U01i = A01i * cz - A01r * sz;
        float U10r = A10r * cz - A10i * sz, U10i = A10i * cz + A10r * sz;
        float U11r = A11r * cz - A11i * sz, U11i = A11i * cz + A11r * sz;
        float V00r, V00i, V01r, V01i, V10r, V10i, V11r, V11i;
        if ((i & 1) == 0) {
            V00r = U01i; V00i = -U01r;
            V01r = U00i; V01i = -U00r;
            V10r = U11i; V10i = -U11r;
            V11r = U10i; V11i = -U10r;
        } else {
            V00r = U01r;  V00i = U01i;
            V01r = -U00r; V01i = -U00i;
            V10r = U11r;  V10i = U11i;
            V11r = -U10r; V11i = -U10i;
        }
        const float xx = (i & 1) ? (step * (float)gb) : (step * (float)ga);
        float se, ce;
        sincosf(0.5f * xx, &se, &ce);
        float* o = gates + tid * 8;
        o[0] = ce * U00r + se * V00r;  o[1] = ce * U00i + se * V00i;
        o[2] = ce * U01r + se * V01r;  o[3] = ce * U01i + se * V01i;
        o[4] = ce * U10r + se * V10r;  o[5] = ce * U10i + se * V10i;
        o[6] = ce * U11r + se * V11r;  o[7] = ce * U11i + se * V11i;
    }

    float ar = (tid == 0) ? 1.0f : 0.0f;
    float ai = 0.0f;
    __syncthreads();

    for (int l = 0; l < N_LAYERS; ++l) {
        #pragma unroll
        for (int i = 0; i < 8; ++i) {
            const float* gm = gates + (l * 8 + i) * 8;
            const int p = 7 - i;
            const int m = 1 << p;
            const int bit = (tid >> p) & 1;
            amps[tid] = make_float2(ar, ai);
            __syncthreads();
            float2 other = amps[tid ^ m];
            float a0r = bit ? other.x : ar, a0i = bit ? other.y : ai;
            float a1r = bit ? ar : other.x, a1i = bit ? ai : other.y;
            float c0r = gm[bit * 4 + 0], c0i = gm[bit * 4 + 1];
            float c1r = gm[bit * 4 + 2], c1i = gm[bit * 4 + 3];
            float nr = c0r * a0r - c0i * a0i + c1r * a1r - c1i * a1i;
            float ni = c0r * a0i + c0i * a0r + c1r * a1i + c1i * a1r;
            __syncthreads();
            ar = nr; ai = ni;
        }
        amps[tid] = make_float2(ar, ai);
        __syncthreads();
        float2 src = amps[tid ^ (tid >> 1)];
        ar = src.x; ai = src.y;
        __syncthreads();
    }

    float p = ar * ar + ai * ai;
    float ev[8];
    #pragma unroll
    for (int i = 0; i < 8; ++i) ev[i] = ((tid >> (7 - i)) & 1) ? -p : p;
    #pragma unroll
    for (int i = 0; i < 8; ++i) {
        #pragma unroll
        for (int s = 1; s < 64; s <<= 1) ev[i] += __shfl_xor(ev[i], s);
    }
    const int wave = tid >> 6, lane = tid & 63;
    if (lane == 0) {
        #pragma unroll
        for (int i = 0; i < 8; ++i) partial[wave][i] = ev[i];
    }
    __syncthreads();
    if (tid < 8) {
        E[tid * NG2 + g] = partial[0][tid] + partial[1][tid] + partial[2][tid] + partial[3][tid];
    }
}

// ---------------------------------------------------------------------------
// Fused separable 2D DFT writing MFMA-B-fragment-ordered f16 (r15-proven,
// byte-identical). Grid (64, 8) = (kp, i); kp/l >= 49 write zeros (K-pad).
// ---------------------------------------------------------------------------
__global__ __launch_bounds__(64) void dft2(const float* __restrict__ E,
                                           _Float16* __restrict__ Fb) {
    const int kp = blockIdx.x, i = blockIdx.y, t = threadIdx.x;
    __shared__ float Es[NG2];
    __shared__ float H[NG];
    const float step = (float)(2.0 * M_PI / 49.0);

    if (kp < NG) {
        for (int e = t; e < NG2; e += 64) Es[e] = E[i * NG2 + e];
    }
    __syncthreads();

    if (kp < NG && t < NG) {
        const int b = t;
        float acc = 0.f;
        if (kp == 0) {
            for (int a = 0; a < NG; ++a) acc += Es[a * NG + b];
            acc *= (1.0f / 49.0f);
        } else {
            const int n = (kp + 1) >> 1;
            float cs, ss;
            sincosf(step * (float)n, &ss, &cs);
            float ca = 1.f, sa = 0.f;
            const bool use_cos = (kp & 1);
            for (int a = 0; a < NG; ++a) {
                acc = fmaf(Es[a * NG + b], use_cos ? ca : sa, acc);
                float cn = ca * cs - sa * ss;
                float sn = sa * cs + ca * ss;
                ca = cn; sa = sn;
            }
            acc *= (2.0f / 49.0f);
        }
        H[b] = acc;
    }
    __syncthreads();

    const int l = t;
    const float PI = 3.14159265358979323846f;
    float acc = 0.f;
    if (kp < NG && l < NG) {
        if (l == 0) {
            for (int b = 0; b < NG; ++b) acc += H[b];
            acc *= (PI / 49.0f);
        } else {
            const int n = (l + 1) >> 1;
            float cs, ss;
            sincosf(step * (float)n, &ss, &cs);
            float cb = 1.f, sb = 0.f;
            const bool use_cos = (l & 1);
            for (int b = 0; b < NG; ++b) {
                acc = fmaf(H[b], use_cos ? cb : sb, acc);
                float cn = cb * cs - sb * ss;
                float sn = sb * cs + cb * ss;
                cb = cn; sb = sn;
            }
            acc *= (2.0f * PI / 49.0f);
        }
    }
    {
        const int ntile = kp >> 4, n = kp & 15;
        const int chunk = l >> 5, lrem = l & 31;
        const int q = lrem >> 3, j = lrem & 7;
        const int fid = (i * 4 + ntile) * 2 + chunk;
        Fb[fid * 512 + (q * 16 + n) * 8 + j] = (_Float16)acc;
    }
}

// ---------------------------------------------------------------------------
// MFMA contraction, ALL 8 OUTPUTS PER BLOCK. Block = 64 batches (4 waves x
// 16); the 4 i-pairs are processed sequentially (unroll 1: bfrag/acc regs
// reused), so the per-batch costs that r15 replicated across 4 blocks — xs
// load, sincos, A-fragment build, v0 LDS table — are paid ONCE.
// Stage-1 MFMA and epilogue per i-pair are byte-equivalent to r15's
// (layouts m89/m120-verified + r15 HW-validated).
// ---------------------------------------------------------------------------
#define V0PAD 68

__global__ __launch_bounds__(256) void contract_mfma(const float* __restrict__ x,
                                                     const _Float16* __restrict__ Fb,
                                                     float* __restrict__ out, int B) {
    __shared__ float xs0[64], xs1[64];
    __shared__ float v0t[64 * V0PAD];  // 17.4 KB

    const int tid = threadIdx.x;
    const int bbase = blockIdx.x * 64;
    if (bbase >= B) return;

    if (tid < 64) {
        float2 xv = ((const float2*)x)[bbase + tid];
        xs0[tid] = xv.x;
        xs1[tid] = xv.y;
    }
    __syncthreads();

    // ---- v0 table: thread t -> batch b=t&63, k-segment s=t>>6 (16 k's) ----
    {
        const int b = tid & 63, s = tid >> 6;
        const float x0 = xs0[b];
        float c1, s1;
        sincosf(x0, &s1, &c1);
        float cb, sb;
        sincosf((float)(8 * s) * x0, &sb, &cb);
        float* row = v0t + b * V0PAD + 16 * s;
        const int k0 = 16 * s;
        row[0] = (k0 == 0) ? 1.0f : ((k0 < NG) ? sb : 0.0f);
        float cm = cb, sm = sb;
        #pragma unroll
        for (int j = 1; j < 16; ++j) {
            if (j & 1) {
                float c2 = cm * c1 - sm * s1, s2 = sm * c1 + cm * s1;
                cm = c2; sm = s2;
            }
            float val = (j & 1) ? cm : sm;
            row[j] = ((k0 + j) < NG) ? val : 0.0f;
        }
    }

    const int lane = tid & 63;
    const int w = tid >> 6;
    const int q = lane >> 4;

    // ---- A fragments (built once, reused for all 4 i-pairs) ----
    const float x1v = xs1[w * 16 + (lane & 15)];
    float c1, s1;
    sincosf(x1v, &s1, &c1);
    half8 afrag[2];
    #pragma unroll
    for (int c = 0; c < 2; ++c) {
        const int l0 = c * 32 + q * 8;
        float cb, sb;
        sincosf((float)(l0 >> 1) * x1v, &sb, &cb);
        float vals[8];
        vals[0] = (l0 == 0) ? 1.0f : sb;
        float cm = cb, sm = sb;
        #pragma unroll
        for (int j = 1; j < 8; ++j) {
            if (j & 1) {
                float c2 = cm * c1 - sm * s1, s2 = sm * c1 + cm * s1;
                cm = c2; sm = s2;
            }
            vals[j] = (j & 1) ? cm : sm;
        }
        #pragma unroll
        for (int j = 0; j < 8; ++j) {
            afrag[c][j] = (_Float16)(((l0 + j) < 52) ? vals[j] : 0.0f);
        }
    }

    __syncthreads();  // v0t ready

    const half8* FB = (const half8*)Fb;

    #pragma unroll 1
    for (int ip = 0; ip < 4; ++ip) {
        const int i0 = ip * 2;

        // B fragments for this i-pair (L2-hot, 16 x 16B vector loads)
        half8 bfrag[16];
        #pragma unroll
        for (int ii = 0; ii < 2; ++ii)
            #pragma unroll
            for (int nt = 0; nt < 4; ++nt)
                #pragma unroll
                for (int c = 0; c < 2; ++c) {
                    const int fid = ((i0 + ii) * 4 + nt) * 2 + c;
                    bfrag[(ii * 4 + nt) * 2 + c] = FB[fid * 64 + lane];
                }

        f32x4 acc[8];
        #pragma unroll
        for (int t = 0; t < 8; ++t) {
            f32x4 z = {0.f, 0.f, 0.f, 0.f};
            acc[t] = __builtin_amdgcn_mfma_f32_16x16x32_f16(afrag[0], bfrag[t * 2 + 0], z, 0, 0, 0);
            acc[t] = __builtin_amdgcn_mfma_f32_16x16x32_f16(afrag[1], bfrag[t * 2 + 1], acc[t], 0, 0, 0);
        }

        float res[2][4];
        #pragma unroll
        for (int ii = 0; ii < 2; ++ii)
            #pragma unroll
            for (int r = 0; r < 4; ++r) res[ii][r] = 0.f;

        #pragma unroll
        for (int ii = 0; ii < 2; ++ii)
            #pragma unroll
            for (int nt = 0; nt < 4; ++nt) {
                f32x4 a = acc[ii * 4 + nt];
                #pragma unroll
                for (int r = 0; r < 4; ++r) {
                    const int bloc = w * 16 + q * 4 + r;
                    float v0 = v0t[bloc * V0PAD + nt * 16 + (lane & 15)];
                    res[ii][r] = fmaf(a[r], v0, res[ii][r]);
                }
            }

        #pragma unroll
        for (int ii = 0; ii < 2; ++ii)
            #pragma unroll
            for (int r = 0; r < 4; ++r) {
                float v = res[ii][r];
                v += __shfl_xor(v, 1);
                v += __shfl_xor(v, 2);
                v += __shfl_xor(v, 4);
                v += __shfl_xor(v, 8);
                res[ii][r] = v;
            }

        if ((lane & 15) == 0) {
            #pragma unroll
            for (int r = 0; r < 4; ++r) {
                const int b = bbase + w * 16 + q * 4 + r;
                out[(size_t)b * 8 + i0 + 0] = res[0][r];
                out[(size_t)b * 8 + i0 + 1] = res[1][r];
            }
        }
    }
}

extern "C" void kernel_launch(void* const* d_in, const int* in_sizes, int n_in,
                              void* d_out, int out_size, void* d_ws, size_t ws_size,
                              hipStream_t stream) {
    (void)n_in; (void)out_size; (void)ws_size;
    const float* x = (const float*)d_in[0];
    const float* w = (const float*)d_in[1];
    float* out = (float*)d_out;
    char* ws = (char*)d_ws;
    float* E = (float*)(ws + WS_E_OFF);
    _Float16* Fb = (_Float16*)(ws + WS_FB_OFF);
    const int B = in_sizes[0] / 2;

    hipLaunchKernelGGL(qnn_grid_lds, dim3(NG2), dim3(256), 0, stream, w, E);
    hipLaunchKernelGGL(dft2, dim3(64, 8), dim3(64), 0, stream, E, Fb);
    hipLaunchKernelGGL(contract_mfma, dim3((B + 63) / 64, 1), dim3(256), 0, stream,
                       x, Fb, out, B);
}